// Round 6
// baseline (204.194 us; speedup 1.0000x reference)
//
#include <hip/hip_runtime.h>
#include <hip/hip_bf16.h>

// ---------------------------------------------------------------------------
// PlainSelfAttention (2quad, tau-scaled) on MI355X.
//  x[2,2048,1024] fp32, Wqkv[1024,3072], Wo[1024,1024], tau[16]
// R6: attn -> 128-thread blocks (2 waves x 32q), 64k KV tiles, 18.4KB LDS
//     (8 blocks/CU reachable), no cross-wave combine. GEMM staging reverted
//     to padded reg-staging (R5's gload_lds variant measured -14us worse).
//     transpose_v folded into gemm_qkv epilogue (writes vT directly).
// ---------------------------------------------------------------------------

typedef unsigned short ushort_t;
typedef __attribute__((ext_vector_type(8))) short short8;
typedef __attribute__((ext_vector_type(4))) float f32x4;
typedef __attribute__((ext_vector_type(16))) float f32x16;

#define B_      2
#define T_      2048
#define C_      1024
#define HEADS_  16
#define D_      64

union frag_u { unsigned u[4]; short8 s8; };

__device__ __forceinline__ ushort_t f2bf(float f) {
  __hip_bfloat16 h = __float2bfloat16(f);           // RNE
  return *reinterpret_cast<ushort_t*>(&h);
}

__device__ __forceinline__ unsigned cvt_pk_bf16(float lo, float hi) {
  unsigned r;
  asm("v_cvt_pk_bf16_f32 %0, %1, %2" : "=v"(r) : "v"(lo), "v"(hi));
  return r;
}

__device__ __forceinline__ void permlane32_swap(unsigned &a, unsigned &b) {
  asm volatile("v_permlane32_swap_b32 %0, %1" : "+v"(a), "+v"(b));
}

__device__ __forceinline__ f32x16 zero16() {
  f32x16 z;
#pragma unroll
  for (int i = 0; i < 16; ++i) z[i] = 0.f;
  return z;
}

// -------------------------- cast x (fp32 -> bf16) --------------------------
__global__ __launch_bounds__(256) void cast_x_kernel(const float* __restrict__ x,
                                                     ushort_t* __restrict__ xb) {
  int i = blockIdx.x * 256 + threadIdx.x;
  float4 f = ((const float4*)x)[i];
  ushort_t* o = xb + (size_t)i * 4;
  o[0] = f2bf(f.x); o[1] = f2bf(f.y); o[2] = f2bf(f.z); o[3] = f2bf(f.w);
}

// ------------------ transpose + cast weights (fp32->bf16) ------------------
__global__ __launch_bounds__(256) void transpose_cast_w(const float* __restrict__ in,
                                                        ushort_t* __restrict__ out,
                                                        int R, int Cc) {
  __shared__ float tile[64][65];
  int rb = blockIdx.y, cb = blockIdx.x;
  int c = threadIdx.x & 63;
  int r0 = threadIdx.x >> 6;
#pragma unroll
  for (int i = 0; i < 16; ++i) {
    int r = r0 + i * 4;
    tile[r][c] = in[(size_t)(rb * 64 + r) * Cc + cb * 64 + c];
  }
  __syncthreads();
#pragma unroll
  for (int i = 0; i < 16; ++i) {
    int r = r0 + i * 4;
    out[(size_t)(cb * 64 + r) * R + rb * 64 + c] = f2bf(tile[c][r]);
  }
}

// -------------------- shared GEMM mainloop (bf16 MFMA) ---------------------
// A: [M][K] bf16 row-major; Bt: [N][K] bf16 row-major. 128x128 tile, BK=64,
// 256 threads (4 waves, 2x2 of 64x64). LDS rows padded to 72 elems (144B) ->
// fragment ds_read_b128 <=2-way bank aliasing (free). Reg-staged: measured
// faster than the linear-LDS global_load_lds variant at these shapes (R5).
__device__ __forceinline__ void gemm_tile(const ushort_t* __restrict__ A,
                                          const ushort_t* __restrict__ Bt,
                                          int K, int tm, int tn,
                                          ushort_t* lds, f32x4 acc[4][4]) {
  const int tid = threadIdx.x;
  const int lane = tid & 63, wave = tid >> 6;
  const int wm = wave >> 1, wn = wave & 1;
  const int lr = lane & 15, lk = lane >> 4;
  ushort_t* As = lds;               // [128][72]
  ushort_t* Bs = lds + 128 * 72;    // [128][72]
  const ushort_t* Ag = A + (size_t)tm * 128 * K;
  const ushort_t* Bg = Bt + (size_t)tn * 128 * K;

  for (int kt = 0; kt < K; kt += 64) {
#pragma unroll
    for (int i = 0; i < 4; ++i) {
      int cch = tid + i * 256; int row = cch >> 3, kc = cch & 7;
      *(short8*)&As[row * 72 + kc * 8] =
          *(const short8*)&Ag[(size_t)row * K + kt + kc * 8];
    }
#pragma unroll
    for (int i = 0; i < 4; ++i) {
      int cch = tid + i * 256; int row = cch >> 3, kc = cch & 7;
      *(short8*)&Bs[row * 72 + kc * 8] =
          *(const short8*)&Bg[(size_t)row * K + kt + kc * 8];
    }
    __syncthreads();
#pragma unroll
    for (int kk = 0; kk < 64; kk += 32) {
      short8 a[4], b[4];
#pragma unroll
      for (int m = 0; m < 4; ++m)
        a[m] = *(const short8*)&As[(wm * 64 + m * 16 + lr) * 72 + kk + lk * 8];
#pragma unroll
      for (int n = 0; n < 4; ++n)
        b[n] = *(const short8*)&Bs[(wn * 64 + n * 16 + lr) * 72 + kk + lk * 8];
#pragma unroll
      for (int m = 0; m < 4; ++m)
#pragma unroll
        for (int n = 0; n < 4; ++n)
          acc[m][n] = __builtin_amdgcn_mfma_f32_16x16x32_bf16(a[m], b[n], acc[m][n], 0, 0, 0);
    }
    __syncthreads();
  }
}

// ------------- GEMM1: qkv = xb @ Wqkv^T, scatter (V transposed) ------------
// q,k written [B*H][T][64]; V written DIRECTLY transposed [B*H][64][T]
// (same 64 scalar stores per thread, different addresses; saves the
// transpose_v kernel's 16.8MB round trip).
__global__ __launch_bounds__(256) void gemm_qkv(const ushort_t* __restrict__ xb,
                                                const ushort_t* __restrict__ wT,
                                                ushort_t* __restrict__ qg,
                                                ushort_t* __restrict__ kg,
                                                ushort_t* __restrict__ vTg) {
  __shared__ __align__(16) ushort_t lds[2 * 128 * 72];
  f32x4 acc[4][4];
#pragma unroll
  for (int m = 0; m < 4; ++m)
#pragma unroll
    for (int n = 0; n < 4; ++n) acc[m][n] = (f32x4){0.f, 0.f, 0.f, 0.f};

  gemm_tile(xb, wT, C_, blockIdx.y, blockIdx.x, lds, acc);

  const int lane = threadIdx.x & 63, wave = threadIdx.x >> 6;
  const int wm = wave >> 1, wn = wave & 1;
  const int lr = lane & 15, lk = lane >> 4;
#pragma unroll
  for (int m = 0; m < 4; ++m)
#pragma unroll
    for (int n = 0; n < 4; ++n)
#pragma unroll
      for (int r = 0; r < 4; ++r) {
        int row = blockIdx.y * 128 + wm * 64 + m * 16 + lk * 4 + r;  // = b*T + t
        int col = blockIdx.x * 128 + wn * 64 + n * 16 + lr;          // [0,3072)
        int b = row >> 11, t = row & 2047;
        int part = col >> 10, idx = col & 1023;
        int h = idx >> 6, j = idx & 63;
        ushort_t val = f2bf(acc[m][n][r]);
        size_t bh = (size_t)(b * HEADS_ + h);
        if (part == 0)      qg[(bh * T_ + t) * D_ + j] = val;
        else if (part == 1) kg[(bh * T_ + t) * D_ + j] = val;
        else                vTg[(bh * D_ + j) * T_ + t] = val;   // transposed
      }
}

// ---------------------- GEMM2: out = attn_bf16 @ Wo^T ----------------------
__global__ __launch_bounds__(256) void gemm_out(const ushort_t* __restrict__ ab,
                                                const ushort_t* __restrict__ woT,
                                                float* __restrict__ out) {
  __shared__ __align__(16) ushort_t lds[2 * 128 * 72];
  f32x4 acc[4][4];
#pragma unroll
  for (int m = 0; m < 4; ++m)
#pragma unroll
    for (int n = 0; n < 4; ++n) acc[m][n] = (f32x4){0.f, 0.f, 0.f, 0.f};

  gemm_tile(ab, woT, C_, blockIdx.y, blockIdx.x, lds, acc);

  const int lane = threadIdx.x & 63, wave = threadIdx.x >> 6;
  const int wm = wave >> 1, wn = wave & 1;
  const int lr = lane & 15, lk = lane >> 4;
#pragma unroll
  for (int m = 0; m < 4; ++m)
#pragma unroll
    for (int n = 0; n < 4; ++n)
#pragma unroll
      for (int r = 0; r < 4; ++r) {
        int row = blockIdx.y * 128 + wm * 64 + m * 16 + lk * 4 + r;
        int col = blockIdx.x * 128 + wn * 64 + n * 16 + lr;
        out[(size_t)row * C_ + col] = acc[m][n][r];
      }
}

// --------------------------- fused 2quad attention -------------------------
// Block: 128 threads = 2 waves, each wave owns 32 q-rows end-to-end (no
// cross-wave combine). KV tile = 64k, LDS 18.4KB -> 8 blocks/CU by LDS;
// VGPR target <=128 for 4 waves/SIMD (~50% occupancy at grid 1024).
// Swapped QK^T (mfma(K,Q), 32x32x16): lane holds E^T[k][q] in regs; PV
// A-frags via cvt_pk_bf16 + permlane32_swap (layout verified R3).
__global__ __launch_bounds__(128, 2) void attn_kernel(const ushort_t* __restrict__ qg,
                                                      const ushort_t* __restrict__ kg,
                                                      const ushort_t* __restrict__ vTg,
                                                      const float* __restrict__ tau,
                                                      ushort_t* __restrict__ attn_out) {
  __shared__ __align__(16) ushort_t Ks[64 * 72];    // [64 k][72] rows=k cols=d
  __shared__ __align__(16) ushort_t Vts[64 * 72];   // [64 d][72] rows=d cols=k
  __shared__ float denom_sh[2][32];                 // [wave][q]

  const int tid = threadIdx.x, lane = tid & 63;
  const int w = tid >> 6;                      // wave = q-group
  const int l31 = lane & 31, hi = lane >> 5, hi8 = hi * 8;
  const int qt = blockIdx.x, bh = blockIdx.y;
  const int b = bh >> 4, h = bh & 15;
  const float inv = 1.0f / (8.0f * tau[h]);    // sqrt(64)*tau

  const ushort_t* kb_ = kg  + (size_t)bh * T_ * D_;
  const ushort_t* vb_ = vTg + (size_t)bh * D_ * T_;
  const ushort_t* qp  = qg  + ((size_t)bh * T_ + qt * 64 + w * 32) * D_;

  // Q B-frags, loop-invariant: lane q-col = l31, d-elems dc*16 + hi8 + j
  short8 qf[4];
#pragma unroll
  for (int dc = 0; dc < 4; ++dc)
    qf[dc] = *(const short8*)&qp[l31 * D_ + dc * 16 + hi8];

  f32x16 acc[2];      // [db]: D[q=crow(r,hi)][d=db*32+l31]
  acc[0] = zero16(); acc[1] = zero16();
  float denomp = 0.f;                          // per-lane partial for q=l31

  for (int kv0 = 0; kv0 < T_; kv0 += 64) {
    // stage K [64][64] and Vt [64][64] (rows padded to 72); 128 threads
#pragma unroll
    for (int p = 0; p < 4; ++p) {
      int idx = p * 1024 + tid * 8;            // 0..4095
      int row = idx >> 6, col = idx & 63;
      *(short8*)&Ks[row * 72 + col] =
          *(const short8*)&kb_[(size_t)(kv0 + row) * D_ + col];
    }
#pragma unroll
    for (int p = 0; p < 4; ++p) {
      int idx = p * 1024 + tid * 8;
      int row = idx >> 6, col = idx & 63;
      *(short8*)&Vts[row * 72 + col] =
          *(const short8*)&vb_[(size_t)row * T_ + kv0 + col];
    }
    __syncthreads();

#pragma unroll
    for (int kb = 0; kb < 2; ++kb) {
      // S^T = K-rows x Q-rows : D[k=crow(r,hi)][q=l31]
      f32x16 s = zero16();
#pragma unroll
      for (int dc = 0; dc < 4; ++dc) {
        short8 kf = *(const short8*)&Ks[(kb * 32 + l31) * 72 + dc * 16 + hi8];
        s = __builtin_amdgcn_mfma_f32_32x32x16_bf16(kf, qf[dc], s, 0, 0, 0);
      }

      // e = (s*inv+5)^2 in regs; reg-local denom; pack to PV A-frags
      float ev[16];
      float dsum = 0.f;
#pragma unroll
      for (int r = 0; r < 16; ++r) {
        float t = fmaf(s[r], inv, 5.0f);
        ev[r] = t * t;
        dsum += ev[r];
      }
      denomp += dsum;
      unsigned P[8];
#pragma unroll
      for (int p = 0; p < 8; ++p) P[p] = cvt_pk_bf16(ev[2 * p], ev[2 * p + 1]);
      frag_u ef[2];
      unsigned a0 = P[0], b0 = P[2]; permlane32_swap(a0, b0);
      unsigned a1 = P[1], b1 = P[3]; permlane32_swap(a1, b1);
      ef[0].u[0] = a0; ef[0].u[1] = a1; ef[0].u[2] = b0; ef[0].u[3] = b1;
      unsigned a2 = P[4], b2 = P[6]; permlane32_swap(a2, b2);
      unsigned a3 = P[5], b3 = P[7]; permlane32_swap(a3, b3);
      ef[1].u[0] = a2; ef[1].u[1] = a3; ef[1].u[2] = b2; ef[1].u[3] = b3;

      // PV: acc[db] += E[q][k-chunk] x V[k-chunk][d]
#pragma unroll
      for (int c = 0; c < 2; ++c)
#pragma unroll
        for (int db = 0; db < 2; ++db) {
          short8 vf = *(const short8*)&Vts[(db * 32 + l31) * 72 + kb * 32 + c * 16 + hi8];
          acc[db] = __builtin_amdgcn_mfma_f32_32x32x16_bf16(ef[c].s8, vf, acc[db], 0, 0, 0);
        }
    }
    __syncthreads();
  }

  // epilogue: denom for q=l31 lives split across hi halves; combine, stash,
  // re-read per output row (crow(r,hi)).
  float dv = denomp + __shfl_xor(denomp, 32);
  if (lane < 32) denom_sh[w][l31] = dv;
  __syncthreads();

#pragma unroll
  for (int db = 0; db < 2; ++db)
#pragma unroll
    for (int r = 0; r < 16; ++r) {
      int qlocal = (r & 3) + 8 * (r >> 2) + 4 * hi;
      float dt = denom_sh[w][qlocal];
      float o = acc[db][r] / (dt + 1e-6f);
      int grow = b * T_ + qt * 64 + w * 32 + qlocal;
      attn_out[(size_t)grow * C_ + h * 64 + db * 32 + l31] = f2bf(o);
    }
}

// ---------------------------------------------------------------------------
extern "C" void kernel_launch(void* const* d_in, const int* in_sizes, int n_in,
                              void* d_out, int out_size, void* d_ws, size_t ws_size,
                              hipStream_t stream) {
  const float* x    = (const float*)d_in[0];
  const float* Wqkv = (const float*)d_in[1];
  const float* Wo   = (const float*)d_in[2];
  const float* tau  = (const float*)d_in[3];
  float* out = (float*)d_out;

  char* ws = (char*)d_ws;
  ushort_t* xb    = (ushort_t*)(ws);                 //  8,388,608 B
  ushort_t* wqkvT = (ushort_t*)(ws + 8388608);       //  6,291,456 B
  ushort_t* woT   = (ushort_t*)(ws + 14680064);      //  2,097,152 B
  ushort_t* qg    = (ushort_t*)(ws + 16777216);      //  8,388,608 B
  ushort_t* kg    = (ushort_t*)(ws + 25165824);      //  8,388,608 B
  ushort_t* ab    = (ushort_t*)(ws + 33554432);      //  8,388,608 B  (total ~42 MB)
  // vT scratch lives in d_out (8.4MB of 16.8MB) — fully consumed by
  // attn_kernel before gemm_out overwrites d_out with the fp32 result.
  ushort_t* vTg = (ushort_t*)d_out;

  cast_x_kernel<<<4096, 256, 0, stream>>>(x, xb);
  transpose_cast_w<<<dim3(48, 16), 256, 0, stream>>>(Wqkv, wqkvT, 1024, 3072);
  transpose_cast_w<<<dim3(16, 16), 256, 0, stream>>>(Wo, woT, 1024, 1024);
  gemm_qkv<<<dim3(24, 32), 256, 0, stream>>>(xb, wqkvT, qg, kg, vTg);
  attn_kernel<<<dim3(32, 32), 128, 0, stream>>>(qg, kg, vTg, tau, ab);
  gemm_out<<<dim3(8, 32), 256, 0, stream>>>(ab, woT, out);
}

// Round 7
// 127.271 us; speedup vs baseline: 1.6044x; 1.6044x over previous
//
#include <hip/hip_runtime.h>
#include <hip/hip_bf16.h>

// ---------------------------------------------------------------------------
// PlainSelfAttention (2quad, tau-scaled) on MI355X.
//  x[2,2048,1024] fp32, Wqkv[1024,3072], Wo[1024,1024], tau[16]
// R7: restore R3 (best measured: attn 54.4us, rest 71.7us), then add T14
//     async-STAGE split to attn: issue tile t+1 global loads before tile t
//     compute, ds_write after. R6 lessons kept: no vT scatter-write from
//     GEMM epilogue (separate LDS transpose kernel), no 128-thread blocks.
// ---------------------------------------------------------------------------

typedef unsigned short ushort_t;
typedef __attribute__((ext_vector_type(8))) short short8;
typedef __attribute__((ext_vector_type(4))) float f32x4;
typedef __attribute__((ext_vector_type(16))) float f32x16;

#define B_      2
#define T_      2048
#define C_      1024
#define HEADS_  16
#define D_      64

union frag_u { unsigned u[4]; short8 s8; };

__device__ __forceinline__ ushort_t f2bf(float f) {
  __hip_bfloat16 h = __float2bfloat16(f);           // RNE
  return *reinterpret_cast<ushort_t*>(&h);
}

__device__ __forceinline__ unsigned cvt_pk_bf16(float lo, float hi) {
  unsigned r;
  asm("v_cvt_pk_bf16_f32 %0, %1, %2" : "=v"(r) : "v"(lo), "v"(hi));
  return r;
}

__device__ __forceinline__ void permlane32_swap(unsigned &a, unsigned &b) {
  asm volatile("v_permlane32_swap_b32 %0, %1" : "+v"(a), "+v"(b));
}

__device__ __forceinline__ f32x16 zero16() {
  f32x16 z;
#pragma unroll
  for (int i = 0; i < 16; ++i) z[i] = 0.f;
  return z;
}

// -------------------------- cast x (fp32 -> bf16) --------------------------
__global__ __launch_bounds__(256) void cast_x_kernel(const float* __restrict__ x,
                                                     ushort_t* __restrict__ xb) {
  int i = blockIdx.x * 256 + threadIdx.x;
  float4 f = ((const float4*)x)[i];
  ushort_t* o = xb + (size_t)i * 4;
  o[0] = f2bf(f.x); o[1] = f2bf(f.y); o[2] = f2bf(f.z); o[3] = f2bf(f.w);
}

// ------------------ transpose + cast weights (fp32->bf16) ------------------
__global__ __launch_bounds__(256) void transpose_cast_w(const float* __restrict__ in,
                                                        ushort_t* __restrict__ out,
                                                        int R, int Cc) {
  __shared__ float tile[64][65];
  int rb = blockIdx.y, cb = blockIdx.x;
  int c = threadIdx.x & 63;
  int r0 = threadIdx.x >> 6;
#pragma unroll
  for (int i = 0; i < 16; ++i) {
    int r = r0 + i * 4;
    tile[r][c] = in[(size_t)(rb * 64 + r) * Cc + cb * 64 + c];
  }
  __syncthreads();
#pragma unroll
  for (int i = 0; i < 16; ++i) {
    int r = r0 + i * 4;
    out[(size_t)(cb * 64 + r) * R + rb * 64 + c] = f2bf(tile[c][r]);
  }
}

// ------------------------- transpose v -> vT (bf16) ------------------------
__global__ __launch_bounds__(256) void transpose_v_kernel(const ushort_t* __restrict__ v,
                                                          ushort_t* __restrict__ vT) {
  __shared__ ushort_t tile[64][72];
  int bh = blockIdx.y, tb = blockIdx.x;
  int c = threadIdx.x & 63;
  int r0 = threadIdx.x >> 6;
#pragma unroll
  for (int i = 0; i < 16; ++i) {
    int r = r0 + i * 4;
    tile[r][c] = v[((size_t)bh * T_ + tb * 64 + r) * D_ + c];
  }
  __syncthreads();
#pragma unroll
  for (int i = 0; i < 16; ++i) {
    int r = r0 + i * 4;
    vT[((size_t)bh * D_ + r) * T_ + tb * 64 + c] = tile[c][r];
  }
}

// -------------------- shared GEMM mainloop (bf16 MFMA) ---------------------
__device__ __forceinline__ void gemm_tile(const ushort_t* __restrict__ A,
                                          const ushort_t* __restrict__ Bt,
                                          int K, int tm, int tn,
                                          ushort_t* lds, f32x4 acc[4][4]) {
  const int tid = threadIdx.x;
  const int lane = tid & 63, wave = tid >> 6;
  const int wm = wave >> 1, wn = wave & 1;
  const int lr = lane & 15, lk = lane >> 4;
  ushort_t* As = lds;               // [128][72]
  ushort_t* Bs = lds + 128 * 72;    // [128][72]
  const ushort_t* Ag = A + (size_t)tm * 128 * K;
  const ushort_t* Bg = Bt + (size_t)tn * 128 * K;

  for (int kt = 0; kt < K; kt += 64) {
#pragma unroll
    for (int i = 0; i < 4; ++i) {
      int cch = tid + i * 256; int row = cch >> 3, kc = cch & 7;
      *(short8*)&As[row * 72 + kc * 8] =
          *(const short8*)&Ag[(size_t)row * K + kt + kc * 8];
    }
#pragma unroll
    for (int i = 0; i < 4; ++i) {
      int cch = tid + i * 256; int row = cch >> 3, kc = cch & 7;
      *(short8*)&Bs[row * 72 + kc * 8] =
          *(const short8*)&Bg[(size_t)row * K + kt + kc * 8];
    }
    __syncthreads();
#pragma unroll
    for (int kk = 0; kk < 64; kk += 32) {
      short8 a[4], b[4];
#pragma unroll
      for (int m = 0; m < 4; ++m)
        a[m] = *(const short8*)&As[(wm * 64 + m * 16 + lr) * 72 + kk + lk * 8];
#pragma unroll
      for (int n = 0; n < 4; ++n)
        b[n] = *(const short8*)&Bs[(wn * 64 + n * 16 + lr) * 72 + kk + lk * 8];
#pragma unroll
      for (int m = 0; m < 4; ++m)
#pragma unroll
        for (int n = 0; n < 4; ++n)
          acc[m][n] = __builtin_amdgcn_mfma_f32_16x16x32_bf16(a[m], b[n], acc[m][n], 0, 0, 0);
    }
    __syncthreads();
  }
}

// -------------------- GEMM1: qkv = xb @ Wqkv^T, scatter --------------------
__global__ __launch_bounds__(256) void gemm_qkv(const ushort_t* __restrict__ xb,
                                                const ushort_t* __restrict__ wT,
                                                ushort_t* __restrict__ qg,
                                                ushort_t* __restrict__ kg,
                                                ushort_t* __restrict__ vg) {
  __shared__ __align__(16) ushort_t lds[2 * 128 * 72];
  f32x4 acc[4][4];
#pragma unroll
  for (int m = 0; m < 4; ++m)
#pragma unroll
    for (int n = 0; n < 4; ++n) acc[m][n] = (f32x4){0.f, 0.f, 0.f, 0.f};

  gemm_tile(xb, wT, C_, blockIdx.y, blockIdx.x, lds, acc);

  const int lane = threadIdx.x & 63, wave = threadIdx.x >> 6;
  const int wm = wave >> 1, wn = wave & 1;
  const int lr = lane & 15, lk = lane >> 4;
#pragma unroll
  for (int m = 0; m < 4; ++m)
#pragma unroll
    for (int n = 0; n < 4; ++n)
#pragma unroll
      for (int r = 0; r < 4; ++r) {
        int row = blockIdx.y * 128 + wm * 64 + m * 16 + lk * 4 + r;  // = b*T + t
        int col = blockIdx.x * 128 + wn * 64 + n * 16 + lr;          // [0,3072)
        int b = row >> 11, t = row & 2047;
        int part = col >> 10, idx = col & 1023;
        int h = idx >> 6, j = idx & 63;
        ushort_t* dst = (part == 0) ? qg : (part == 1) ? kg : vg;
        dst[(((size_t)(b * HEADS_ + h)) * T_ + t) * D_ + j] = f2bf(acc[m][n][r]);
      }
}

// ---------------------- GEMM2: out = attn_bf16 @ Wo^T ----------------------
__global__ __launch_bounds__(256) void gemm_out(const ushort_t* __restrict__ ab,
                                                const ushort_t* __restrict__ woT,
                                                float* __restrict__ out) {
  __shared__ __align__(16) ushort_t lds[2 * 128 * 72];
  f32x4 acc[4][4];
#pragma unroll
  for (int m = 0; m < 4; ++m)
#pragma unroll
    for (int n = 0; n < 4; ++n) acc[m][n] = (f32x4){0.f, 0.f, 0.f, 0.f};

  gemm_tile(ab, woT, C_, blockIdx.y, blockIdx.x, lds, acc);

  const int lane = threadIdx.x & 63, wave = threadIdx.x >> 6;
  const int wm = wave >> 1, wn = wave & 1;
  const int lr = lane & 15, lk = lane >> 4;
#pragma unroll
  for (int m = 0; m < 4; ++m)
#pragma unroll
    for (int n = 0; n < 4; ++n)
#pragma unroll
      for (int r = 0; r < 4; ++r) {
        int row = blockIdx.y * 128 + wm * 64 + m * 16 + lk * 4 + r;
        int col = blockIdx.x * 128 + wn * 64 + n * 16 + lr;
        out[(size_t)row * C_ + col] = acc[m][n][r];
      }
}

// --------------------------- fused 2quad attention -------------------------
// R3 structure: block = (bh, 128 q-rows), 4 waves = 2 q-groups x 2 KV-splits,
// KV tile = 128k. Swapped QK^T (mfma(K,Q), 32x32x16), E in registers via
// cvt_pk_bf16 + permlane32_swap; epilogue combines KV halves through LDS.
// R7 adds T14 async-STAGE: tile t+1's global loads are issued right after
// the barrier that publishes tile t, and their LDS write happens after
// tile t's compute -- HBM latency hides under QK/pack/PV (~1000 cy).
__global__ __launch_bounds__(256, 2) void attn_kernel(const ushort_t* __restrict__ qg,
                                                      const ushort_t* __restrict__ kg,
                                                      const ushort_t* __restrict__ vTg,
                                                      const float* __restrict__ tau,
                                                      ushort_t* __restrict__ attn_out) {
  __shared__ __align__(16) ushort_t kvbuf[128 * 72 + 64 * 136];  // Ks | Vts (35.8 KB)
  __shared__ float denom_lds[2][2][2][32];                       // [wk][wq][qb][q]
  ushort_t* Ks  = kvbuf;             // [128 k][72]   rows = k, cols = d
  ushort_t* Vts = kvbuf + 128 * 72;  // [64 d][136]   rows = d, cols = k (128 wide)

  const int tid = threadIdx.x, lane = tid & 63;
  const int w = tid >> 6, wq = w >> 1, wk = w & 1;
  const int l31 = lane & 31, hi = lane >> 5, hi8 = hi * 8;
  const int qt = blockIdx.x, bh = blockIdx.y;
  const int b = bh >> 4, h = bh & 15;
  const float inv = 1.0f / (8.0f * tau[h]);   // sqrt(64)*tau

  const ushort_t* kb_ = kg  + (size_t)bh * T_ * D_;
  const ushort_t* vb_ = vTg + (size_t)bh * D_ * T_;
  const ushort_t* qp  = qg  + ((size_t)bh * T_ + qt * 128 + wq * 64) * D_;

  // per-thread staging coordinates (constant across tiles)
  const int krow[4] = { (tid) >> 3, (tid + 256) >> 3, (tid + 512) >> 3, (tid + 768) >> 3 };
  const int kcol = (tid & 7) * 8;
  const int vrow[4] = { (tid) >> 4, (tid + 256) >> 4, (tid + 512) >> 4, (tid + 768) >> 4 };
  const int vcol = (tid & 15) * 8;

  // Q B-frags in registers, loop-invariant.
  short8 qf[2][4];
#pragma unroll
  for (int qb = 0; qb < 2; ++qb)
#pragma unroll
    for (int dc = 0; dc < 4; ++dc)
      qf[qb][dc] = *(const short8*)&qp[(qb * 32 + l31) * D_ + dc * 16 + hi8];

  f32x16 acc[2][2];   // [qb][db]: D[q=crow(r,hi)][d=db*32+l31]
  acc[0][0] = zero16(); acc[0][1] = zero16();
  acc[1][0] = zero16(); acc[1][1] = zero16();
  float denomp[2] = {0.f, 0.f};

  // ---- prologue: load tile 0 into registers ----
  short8 kreg[4], vreg[4];
#pragma unroll
  for (int i = 0; i < 4; ++i) {
    kreg[i] = *(const short8*)&kb_[(size_t)krow[i] * D_ + kcol];
    vreg[i] = *(const short8*)&vb_[(size_t)vrow[i] * T_ + vcol];
  }

  const int NT = T_ / 128;
  for (int rnd = 0; rnd < NT; ++rnd) {
    // publish tile rnd from regs to LDS
#pragma unroll
    for (int i = 0; i < 4; ++i) {
      *(short8*)&Ks[krow[i] * 72 + kcol] = kreg[i];
      *(short8*)&Vts[vrow[i] * 136 + vcol] = vreg[i];
    }
    __syncthreads();

    // issue tile rnd+1 global loads NOW; consumed only at next publish,
    // so the waitcnt lands after this tile's compute.
    if (rnd + 1 < NT) {
      const int kv0 = (rnd + 1) * 128;
#pragma unroll
      for (int i = 0; i < 4; ++i) {
        kreg[i] = *(const short8*)&kb_[(size_t)(kv0 + krow[i]) * D_ + kcol];
        vreg[i] = *(const short8*)&vb_[(size_t)vrow[i] * T_ + kv0 + vcol];
      }
    }

#pragma unroll
    for (int kb = 0; kb < 2; ++kb) {
      const int krow0 = wk * 64 + kb * 32;     // this wave's 32-k block
      // S^T = K-rows x Q-rows : D[k=crow(r,hi)][q=l31]
      f32x16 s[2]; s[0] = zero16(); s[1] = zero16();
#pragma unroll
      for (int dc = 0; dc < 4; ++dc) {
        short8 kf = *(const short8*)&Ks[(krow0 + l31) * 72 + dc * 16 + hi8];
        s[0] = __builtin_amdgcn_mfma_f32_32x32x16_bf16(kf, qf[0][dc], s[0], 0, 0, 0);
        s[1] = __builtin_amdgcn_mfma_f32_32x32x16_bf16(kf, qf[1][dc], s[1], 0, 0, 0);
      }

      // e = (s*inv+5)^2 in regs; reg-local denom; pack to PV A-frags
      frag_u ef[2][2];
#pragma unroll
      for (int qb = 0; qb < 2; ++qb) {
        float ev[16];
        float dsum = 0.f;
#pragma unroll
        for (int r = 0; r < 16; ++r) {
          float t = fmaf(s[qb][r], inv, 5.0f);
          ev[r] = t * t;
          dsum += ev[r];
        }
        denomp[qb] += dsum;
        unsigned P[8];
#pragma unroll
        for (int p = 0; p < 8; ++p) P[p] = cvt_pk_bf16(ev[2 * p], ev[2 * p + 1]);
        unsigned a0 = P[0], b0 = P[2]; permlane32_swap(a0, b0);
        unsigned a1 = P[1], b1 = P[3]; permlane32_swap(a1, b1);
        ef[qb][0].u[0] = a0; ef[qb][0].u[1] = a1; ef[qb][0].u[2] = b0; ef[qb][0].u[3] = b1;
        unsigned a2 = P[4], b2 = P[6]; permlane32_swap(a2, b2);
        unsigned a3 = P[5], b3 = P[7]; permlane32_swap(a3, b3);
        ef[qb][1].u[0] = a2; ef[qb][1].u[1] = a3; ef[qb][1].u[2] = b2; ef[qb][1].u[3] = b3;
      }

      // PV: acc[qb][db] += E[q][k-chunk] x V[k-chunk][d]
#pragma unroll
      for (int c = 0; c < 2; ++c)
#pragma unroll
        for (int db = 0; db < 2; ++db) {
          short8 vf = *(const short8*)&Vts[(db * 32 + l31) * 136 + krow0 + c * 16 + hi8];
          acc[0][db] = __builtin_amdgcn_mfma_f32_32x32x16_bf16(ef[0][c].s8, vf, acc[0][db], 0, 0, 0);
          acc[1][db] = __builtin_amdgcn_mfma_f32_32x32x16_bf16(ef[1][c].s8, vf, acc[1][db], 0, 0, 0);
        }
    }
    __syncthreads();
  }

  // ---------------- epilogue: combine KV halves, normalize ----------------
#pragma unroll
  for (int qb = 0; qb < 2; ++qb) {
    float v = denomp[qb];
    v += __shfl_xor(v, 32);                    // combine hi halves
    if (lane < 32) denom_lds[wk][wq][qb][l31] = v;
  }
  float* out_lds = (float*)kvbuf;              // [2 wq][64 q][64 d] fp32 (32 KB)
  if (wk == 1) {
#pragma unroll
    for (int qb = 0; qb < 2; ++qb)
#pragma unroll
      for (int db = 0; db < 2; ++db)
#pragma unroll
        for (int r = 0; r < 16; ++r) {
          int qr = qb * 32 + (r & 3) + 8 * (r >> 2) + 4 * hi;
          out_lds[(wq * 64 + qr) * 64 + db * 32 + l31] = acc[qb][db][r];
        }
  }
  __syncthreads();
  if (wk == 0) {
#pragma unroll
    for (int qb = 0; qb < 2; ++qb)
#pragma unroll
      for (int r = 0; r < 16; ++r) {
        int cr = (r & 3) + 8 * (r >> 2) + 4 * hi;
        int qr = qb * 32 + cr;
        float dt = denom_lds[0][wq][qb][cr] + denom_lds[1][wq][qb][cr];
        float dinv = 1.0f / (dt + 1e-6f);
#pragma unroll
        for (int db = 0; db < 2; ++db) {
          float val = acc[qb][db][r] + out_lds[(wq * 64 + qr) * 64 + db * 32 + l31];
          int grow = b * T_ + qt * 128 + wq * 64 + qr;
          attn_out[(size_t)grow * C_ + h * 64 + db * 32 + l31] = f2bf(val * dinv);
        }
      }
  }
}

// ---------------------------------------------------------------------------
extern "C" void kernel_launch(void* const* d_in, const int* in_sizes, int n_in,
                              void* d_out, int out_size, void* d_ws, size_t ws_size,
                              hipStream_t stream) {
  const float* x    = (const float*)d_in[0];
  const float* Wqkv = (const float*)d_in[1];
  const float* Wo   = (const float*)d_in[2];
  const float* tau  = (const float*)d_in[3];
  float* out = (float*)d_out;

  char* ws = (char*)d_ws;
  ushort_t* xb    = (ushort_t*)(ws);                 //  8,388,608 B
  ushort_t* wqkvT = (ushort_t*)(ws + 8388608);       //  6,291,456 B
  ushort_t* woT   = (ushort_t*)(ws + 14680064);      //  2,097,152 B
  ushort_t* qg    = (ushort_t*)(ws + 16777216);      //  8,388,608 B
  ushort_t* kg    = (ushort_t*)(ws + 25165824);      //  8,388,608 B
  ushort_t* ab    = (ushort_t*)(ws + 33554432);      //  8,388,608 B  (total ~42 MB)
  // v and vT scratch live in d_out (16,777,216 B) — consumed before gemm_out
  // overwrites d_out with the final fp32 result.
  ushort_t* vg  = (ushort_t*)d_out;
  ushort_t* vTg = (ushort_t*)d_out + 4194304;

  cast_x_kernel<<<4096, 256, 0, stream>>>(x, xb);
  transpose_cast_w<<<dim3(48, 16), 256, 0, stream>>>(Wqkv, wqkvT, 1024, 3072);
  transpose_cast_w<<<dim3(16, 16), 256, 0, stream>>>(Wo, woT, 1024, 1024);
  gemm_qkv<<<dim3(24, 32), 256, 0, stream>>>(xb, wqkvT, qg, kg, vg);
  transpose_v_kernel<<<dim3(32, 32), 256, 0, stream>>>(vg, vTg);
  attn_kernel<<<dim3(16, 32), 256, 0, stream>>>(qg, kg, vTg, tau, ab);
  gemm_out<<<dim3(8, 32), 256, 0, stream>>>(ab, woT, out);
}